// Round 3
// baseline (172.297 us; speedup 1.0000x reference)
//
#include <hip/hip_runtime.h>
#include <math.h>

// InterContactLoss on MI355X — round 3.
//
// Round-2 evidence: VALU-issue-bound (73% busy), compiler lowered float2
// elementwise ops to SCALAR v_fma_f32 (142M busy cycles ~= scalar cost).
// Round-3 levers:
//  - inline-asm v_pk_fma_f32 with op_sel/op_sel_hi broadcast of the staged
//    B values -> 3 packed fma per 2 rows per j, ZERO splat moves.
//    LDS layout per B vert j: p=(-2bx,-2by), q=(-2bz, bb).
//      t = pk_fma(az2, q.lo bcast, q.hi bcast)   // az*(-2bz) + bb
//      t = pk_fma(ay2, p.hi bcast, t)            // + ay*(-2by)
//      t = pk_fma(ax2, p.lo bcast, t)            // + ax*(-2bx)
//  - v_min3_f32 folds two j's per row per instr: 2.0 VALU/pair total.
//  - 3 graph nodes: memset(min arrays) -> mindist (block0 zeroes acc+ctr)
//    -> reduce+finalize fused (last-done block computes the scalar).

#define BT 16
#define VH 6890
#define VO 2048
#define NH (BT * VH)   // 110240
#define NO (BT * VO)   // 32768

typedef float v2f __attribute__((ext_vector_type(2)));

#define RP 4           // row-pairs per thread (8 rows)

// t = a * q.lo + q.hi   (both halves; broadcast from q)
#define PK_FMA_ZB(t, a, q) \
    asm("v_pk_fma_f32 %0, %1, %2, %2 op_sel:[0,0,1] op_sel_hi:[1,0,1]" \
        : "=v"(t) : "v"(a), "v"(q))
// t = a * p.hi + t
#define PK_FMA_YB(t, a, p) \
    asm("v_pk_fma_f32 %0, %1, %2, %0 op_sel:[0,1,0] op_sel_hi:[1,1,1]" \
        : "+v"(t) : "v"(a), "v"(p))
// t = a * p.lo + t
#define PK_FMA_XB(t, a, p) \
    asm("v_pk_fma_f32 %0, %1, %2, %0 op_sel:[0,0,0] op_sel_hi:[1,0,1]" \
        : "+v"(t) : "v"(a), "v"(p))
// r = min(r, x, y)
#define MIN3(r, x, y) \
    asm("v_min3_f32 %0, %1, %2, %0" : "+v"(r) : "v"(x), "v"(y))

__global__ __launch_bounds__(256, 8)
void mindist_all(const float* __restrict__ hv,  const float* __restrict__ ov,
                 const float* __restrict__ ghv, const float* __restrict__ gov,
                 unsigned int* __restrict__ dh,  unsigned int* __restrict__ dov,
                 unsigned int* __restrict__ dhg, unsigned int* __restrict__ dog,
                 unsigned int* __restrict__ accw)
{
    __shared__ v2f lds2[512];   // per B vert: [2j]=(-2bx,-2by), [2j+1]=(-2bz,bb)

    // zero the loss accumulators + done counter (reduce kernel runs after us)
    if (blockIdx.x == 0 && threadIdx.x < 12) accw[threadIdx.x] = 0u;

    const int idx = blockIdx.x;
    const float *A, *B;
    unsigned int* out;
    int nA, nB, bt, abk, sliceLen, b0;

    if (idx < 1024) {
        // human-owned: rows = human verts (4 groups of 2048), B = object (8 slices of 256)
        const int p = idx >> 9;           // 0 = pred, 1 = gt
        const int r = idx & 511;
        abk = r & 3;
        bt  = (r >> 2) & 15;
        const int z = r >> 6;             // 0..7
        A = p ? ghv : hv;  B = p ? gov : ov;  out = p ? dhg : dh;
        nA = VH; nB = VO; sliceLen = 256; b0 = z * 256;
    } else {
        // object-owned: rows = object verts (2048), B = human (32 slices of 216)
        const int q = idx - 1024;
        const int p = q >> 9;
        const int r = q & 511;
        abk = 0;
        bt  = r & 15;
        const int z = r >> 4;             // 0..31
        A = p ? gov : ov;  B = p ? ghv : hv;  out = p ? dog : dov;
        nA = VO; nB = VH; sliceLen = 216; b0 = z * 216;
    }

    const float* Ab = A + (size_t)bt * nA * 3;
    const float* Bb = B + (size_t)bt * nB * 3;
    const int tid = threadIdx.x;

    // stage B slice
    if (tid < sliceLen) {
        const int gj = b0 + tid;
        if (gj < nB) {
            const float bx = Bb[gj * 3 + 0];
            const float by = Bb[gj * 3 + 1];
            const float bz = Bb[gj * 3 + 2];
            lds2[2 * tid + 0] = (v2f){-2.f * bx, -2.f * by};
            lds2[2 * tid + 1] = (v2f){-2.f * bz, fmaf(bx, bx, fmaf(by, by, bz * bz))};
        } else {
            lds2[2 * tid + 0] = (v2f){0.f, 0.f};
            lds2[2 * tid + 1] = (v2f){0.f, 3.0e38f};   // pad: never the min
        }
    }

    // A rows: row = abk*2048 + tid + m*256, packed as (2k, 2k+1)
    const int rowb = abk * 2048 + tid;
    v2f ax[RP], ay[RP], az[RP];
    float rx[RP], ry[RP];
#pragma unroll
    for (int k = 0; k < RP; ++k) {
        const int r0 = rowb + (2 * k    ) * 256;
        const int r1 = rowb + (2 * k + 1) * 256;
        const int i0 = (r0 < nA) ? r0 : 0;   // clamped load; never stored
        const int i1 = (r1 < nA) ? r1 : 0;
        ax[k] = (v2f){Ab[i0 * 3 + 0], Ab[i1 * 3 + 0]};
        ay[k] = (v2f){Ab[i0 * 3 + 1], Ab[i1 * 3 + 1]};
        az[k] = (v2f){Ab[i0 * 3 + 2], Ab[i1 * 3 + 2]};
        rx[k] = 3.0e38f; ry[k] = 3.0e38f;
    }

    __syncthreads();

    // inner loop: 2 j's per step, 8 per outer iter (216 and 256 both %8==0)
    for (int j0 = 0; j0 < sliceLen; j0 += 8) {
        const v2f* base = &lds2[2 * j0];
#pragma unroll
        for (int jj = 0; jj < 4; ++jj) {
            const v2f p0 = base[4 * jj + 0];
            const v2f q0 = base[4 * jj + 1];
            const v2f p1 = base[4 * jj + 2];
            const v2f q1 = base[4 * jj + 3];
#pragma unroll
            for (int k = 0; k < RP; ++k) {
                v2f tA, tB;
                PK_FMA_ZB(tA, az[k], q0);
                PK_FMA_YB(tA, ay[k], p0);
                PK_FMA_XB(tA, ax[k], p0);
                PK_FMA_ZB(tB, az[k], q1);
                PK_FMA_YB(tB, ay[k], p1);
                PK_FMA_XB(tB, ax[k], p1);
                MIN3(rx[k], tA.x, tB.x);
                MIN3(ry[k], tA.y, tB.y);
            }
        }
    }

    // epilogue: d2 = max(aa + rmin, 0); combine across slices via uint atomicMin
#pragma unroll
    for (int k = 0; k < RP; ++k) {
        const int r0 = rowb + (2 * k    ) * 256;
        const int r1 = rowb + (2 * k + 1) * 256;
        if (r0 < nA) {
            const float aa = fmaf(ax[k].x, ax[k].x, fmaf(ay[k].x, ay[k].x, az[k].x * az[k].x));
            atomicMin(&out[(size_t)bt * nA + r0], __float_as_uint(fmaxf(aa + rx[k], 0.f)));
        }
        if (r1 < nA) {
            const float aa = fmaf(ax[k].y, ax[k].y, fmaf(ay[k].y, ay[k].y, az[k].y * az[k].y));
            atomicMin(&out[(size_t)bt * nA + r1], __float_as_uint(fmaxf(aa + ry[k], 0.f)));
        }
    }
}

// Fused per-element loss + accumulation + last-block finalize.
// acc: [0..3] human {pos, bce_pos, bce_neg, huber}; [4..7] object; acc[8] = done ctr.
#define NBLK_H 431   // ceil(110240/256)
#define NBLK_O 128   // 32768/256
#define NBLK   (NBLK_H + NBLK_O)

__global__ __launch_bounds__(256)
void reduce_finalize(const float* __restrict__ dh2, const float* __restrict__ dhg2,
                     const float* __restrict__ do2, const float* __restrict__ dog2,
                     float* __restrict__ acc, float* __restrict__ outp)
{
    const int b = blockIdx.x;
    const float *p2, *g2;
    float* a4;
    int N, i0;
    if (b < NBLK_H) { p2 = dh2; g2 = dhg2; a4 = acc;     N = NH; i0 = b * 256; }
    else            { p2 = do2; g2 = dog2; a4 = acc + 4; N = NO; i0 = (b - NBLK_H) * 256; }

    const int i = i0 + threadIdx.x;
    float t = 0.f, sp = 0.f, sn = 0.f, sh = 0.f;
    if (i < N) {
        const float d  = sqrtf(p2[i]);
        const float dg = sqrtf(g2[i]);
        const float tt = (dg < 0.2f) ? 1.f : 0.f;

        const float z = (0.2f - d) * 100.0f;           // (DIST_THR - d)/ALPHA
        float p = 1.0f / (1.0f + expf(-z));
        p = fminf(fmaxf(p, 1e-6f), 1.0f - 1e-6f);
        const float bce = (tt > 0.5f) ? -logf(p) : -logf(1.0f - p);

        const float over = fmaxf(d - 0.1f, 0.0f);      // d - CONTACT_TGT
        const float hub  = (over < 0.01f) ? (0.5f * over * over) / 0.01f
                                          : (over - 0.5f * 0.01f);
        t  = tt;
        sp = tt * bce;
        sn = (1.0f - tt) * bce;
        sh = tt * hub;
    }
    for (int off = 32; off > 0; off >>= 1) {
        t  += __shfl_down(t,  off);
        sp += __shfl_down(sp, off);
        sn += __shfl_down(sn, off);
        sh += __shfl_down(sh, off);
    }
    __shared__ float wsum[4][4];
    const int wid = threadIdx.x >> 6, lane = threadIdx.x & 63;
    if (lane == 0) {
        wsum[wid][0] = t; wsum[wid][1] = sp; wsum[wid][2] = sn; wsum[wid][3] = sh;
    }
    __syncthreads();
    if (threadIdx.x == 0) {
        float s0 = 0, s1 = 0, s2 = 0, s3 = 0;
        for (int w = 0; w < 4; ++w) {
            s0 += wsum[w][0]; s1 += wsum[w][1]; s2 += wsum[w][2]; s3 += wsum[w][3];
        }
        atomicAdd(&a4[0], s0);
        atomicAdd(&a4[1], s1);
        atomicAdd(&a4[2], s2);
        atomicAdd(&a4[3], s3);

        __threadfence();
        const unsigned f = atomicAdd((unsigned int*)&acc[8], 1u);
        if (f == NBLK - 1) {
            // all blocks' adds are visible; read via RMW to bypass stale caches
            float v[8];
            for (int q = 0; q < 8; ++q) v[q] = atomicAdd(&acc[q], 0.0f);
            const float Ph = v[0], SpH = v[1], SnH = v[2], ShH = v[3];
            const float Po = v[4], SpO = v[5], SnO = v[6], ShO = v[7];
            const float Nh = (float)NH, No = (float)NO;

            const float pwH = ((Nh - Ph) + 1e-6f) / (Ph + 1e-6f);
            const float pwO = ((No - Po) + 1e-6f) / (Po + 1e-6f);
            const float bceH = (pwH * SpH + SnH) / Nh;
            const float bceO = (pwO * SpO + SnO) / No;
            const float Lbce = 0.5f * (bceH + bceO);

            const float LdH = (Ph > 0.f) ? ShH / fmaxf(Ph, 1.f) : 0.f;
            const float LdO = (Po > 0.f) ? ShO / fmaxf(Po, 1.f) : 0.f;

            outp[0] = 0.5f * Lbce + (LdH + LdO);
        }
    }
}

extern "C" void kernel_launch(void* const* d_in, const int* in_sizes, int n_in,
                              void* d_out, int out_size, void* d_ws, size_t ws_size,
                              hipStream_t stream)
{
    const float* hv  = (const float*)d_in[0];
    const float* ov  = (const float*)d_in[1];
    const float* ghv = (const float*)d_in[2];
    const float* gov = (const float*)d_in[3];

    float* ws  = (float*)d_ws;
    float* dh  = ws;               // [NH] min d^2 human->object
    float* dov = dh  + NH;         // [NO]
    float* dhg = dov + NO;         // [NH] gt
    float* dog = dhg + NH;         // [NO] gt
    float* acc = dog + NO;         // [8] accumulators + [1] done counter

    // 0x7f7f7f7f = 3.3966e38f: > any clamped d^2, order-preserving uint init
    hipMemsetAsync(ws, 0x7f, (size_t)(2 * (NH + NO)) * sizeof(float), stream);

    mindist_all<<<2048, 256, 0, stream>>>(hv, ov, ghv, gov,
                                          (unsigned int*)dh, (unsigned int*)dov,
                                          (unsigned int*)dhg, (unsigned int*)dog,
                                          (unsigned int*)acc);

    reduce_finalize<<<NBLK, 256, 0, stream>>>(dh, dhg, dov, dog, acc, (float*)d_out);
}